// Round 7
// baseline (164.327 us; speedup 1.0000x reference)
//
#include <hip/hip_runtime.h>
#include <math.h>

#define DIM 64
#define NNB 16
#define BATCH 16384

typedef float4 f4;

__device__ __forceinline__ float dot4(const f4 a, const f4 b) {
    return fmaf(a.x, b.x, fmaf(a.y, b.y, fmaf(a.z, b.z, a.w * b.w)));
}

// Sum across the 4 lane-groups (lanes differing in bits 4,5); chunk stays put.
__device__ __forceinline__ f4 xgrp_sum(f4 v) {
    v.x += __shfl_xor(v.x, 16, 64); v.y += __shfl_xor(v.y, 16, 64);
    v.z += __shfl_xor(v.z, 16, 64); v.w += __shfl_xor(v.w, 16, 64);
    v.x += __shfl_xor(v.x, 32, 64); v.y += __shfl_xor(v.y, 32, 64);
    v.z += __shfl_xor(v.z, 32, 64); v.w += __shfl_xor(v.w, 32, 64);
    return v;
}

// Async global->LDS, 16 B/lane, no VGPR destination (can't be "sunk" by RA).
// HW semantics: per-lane global addr, wave-uniform LDS base + lane*16.
__device__ __forceinline__ void gload16(const void* gptr, void* lptr) {
    __builtin_amdgcn_global_load_lds(
        (const __attribute__((address_space(1))) void*)gptr,
        (__attribute__((address_space(3))) void*)lptr, 16, 0, 0);
}

template <int WPB>
__global__ __launch_bounds__(WPB * 64) void klgcn_kernel(
    const int* __restrict__ u, const int* __restrict__ v,
    const int* __restrict__ user_neighbor, const int* __restrict__ item_neighbor,
    const int* __restrict__ adj_ent, const int* __restrict__ adj_rel,
    const float* __restrict__ usr_emb, const float* __restrict__ ent_emb,
    const float* __restrict__ rel_emb, const float* __restrict__ agg_W,
    const float* __restrict__ agg_b, float* __restrict__ out)
{
    const int wave = threadIdx.x >> 6;
    const int lane = threadIdx.x & 63;
    const int g = lane >> 4;   // group 0..3: owns neighbor rows 4g..4g+3
    const int s = lane & 15;   // chunk 0..15: dims [4s, 4s+4)
    const int b = __builtin_amdgcn_readfirstlane(blockIdx.x * WPB + wave);

    // Per-wave staging: 16 gathered rows-of-4 (1 KB each). Identity mapping:
    // lane i writes/reads slot [k][i]. No cross-wave sharing -> no barrier.
    __shared__ f4 stage[WPB][16][64];

    const f4* __restrict__ usr4 = (const f4*)usr_emb;
    const f4* __restrict__ ent4 = (const f4*)ent_emb;
    const f4* __restrict__ rel4 = (const f4*)rel_emb;
    const f4* __restrict__ W4   = (const f4*)agg_W;
    const f4* __restrict__ b4p  = (const f4*)agg_b;
    const int4* __restrict__ it4 = (const int4*)item_neighbor;
    const int4* __restrict__ un4 = (const int4*)user_neighbor;
    const int4* __restrict__ ar4 = (const int4*)adj_rel;
    const int4* __restrict__ ae4 = (const int4*)adj_ent;

    const int ub = __builtin_amdgcn_readfirstlane(u[b]);
    const int vb = __builtin_amdgcn_readfirstlane(v[b]);

    // ---- Index loads (one int4 per table; lane-contiguous).
    const int4 iar = ar4[vb * 4 + g];         // adj_rel rows 4g..4g+3 (2-hop chain)
    const int4 iae = ae4[vb * 4 + g];         // adj_ent rows 4g..4g+3
    const int4 iit = it4[b * 4 + g];          // item_neighbor rows 4g..4g+3
    const int4 iun = un4[b * 4 + g];          // user_neighbor rows 4g..4g+3

    // ---- Direct rows (VGPR loads; only 8 result VGPRs, issued up front).
    const f4 ue4 = usr4[(long)ub * 16 + s];
    const f4 ie4 = ent4[(long)vb * 16 + s];

    // ---- ISSUE PHASE: 16 async gathers, each 4 rows = 1 KB, zero dest VGPRs.
    gload16(&rel4[iar.x * 16 + s],       &stage[wave][0][0]);
    gload16(&rel4[iar.y * 16 + s],       &stage[wave][1][0]);
    gload16(&rel4[iar.z * 16 + s],       &stage[wave][2][0]);
    gload16(&rel4[iar.w * 16 + s],       &stage[wave][3][0]);
    gload16(&ent4[(long)iae.x * 16 + s], &stage[wave][4][0]);
    gload16(&ent4[(long)iae.y * 16 + s], &stage[wave][5][0]);
    gload16(&ent4[(long)iae.z * 16 + s], &stage[wave][6][0]);
    gload16(&ent4[(long)iae.w * 16 + s], &stage[wave][7][0]);
    gload16(&usr4[(long)iit.x * 16 + s], &stage[wave][8][0]);
    gload16(&usr4[(long)iit.y * 16 + s], &stage[wave][9][0]);
    gload16(&usr4[(long)iit.z * 16 + s], &stage[wave][10][0]);
    gload16(&usr4[(long)iit.w * 16 + s], &stage[wave][11][0]);
    gload16(&ent4[(long)iun.x * 16 + s], &stage[wave][12][0]);
    gload16(&ent4[(long)iun.y * 16 + s], &stage[wave][13][0]);
    gload16(&ent4[(long)iun.z * 16 + s], &stage[wave][14][0]);
    gload16(&ent4[(long)iun.w * 16 + s], &stage[wave][15][0]);

    // Drain all 16 in one wait (compiler can't see the LDS dep -> explicit).
    asm volatile("s_waitcnt vmcnt(0)" ::: "memory");

    // ---- CONSUME PHASE (ds_read_b128 at each lane's own slot; conflict-free).
    f4 Re[4], Ag[4];
#pragma unroll
    for (int k = 0; k < 4; k++) Re[k] = stage[wave][k][lane];
#pragma unroll
    for (int k = 0; k < 4; k++) Ag[k] = stage[wave][4 + k][lane];

    // Attention scores: sc[k] = dot(ue, rel_row[4g+k]) (in-group reduce).
    float sc[4];
#pragma unroll
    for (int k = 0; k < 4; k++) {
        float p = dot4(ue4, Re[k]);
        p += __shfl_xor(p, 1, 64); p += __shfl_xor(p, 2, 64);
        p += __shfl_xor(p, 4, 64); p += __shfl_xor(p, 8, 64);
        sc[k] = p;  // identical across the 16 lanes of group g
    }
    float m = fmaxf(fmaxf(sc[0], sc[1]), fmaxf(sc[2], sc[3]));
    m = fmaxf(m, __shfl_xor(m, 16, 64));
    m = fmaxf(m, __shfl_xor(m, 32, 64));
    float e[4];
    float ssum = 0.f;
#pragma unroll
    for (int k = 0; k < 4; k++) { e[k] = __expf(sc[k] - m); ssum += e[k]; }
    ssum += __shfl_xor(ssum, 16, 64);
    ssum += __shfl_xor(ssum, 32, 64);
    const float inv = 1.0f / ssum;

    // neighbors_agg: this lane holds the attn weights for its own rows.
    f4 ag = {0.f, 0.f, 0.f, 0.f};
#pragma unroll
    for (int k = 0; k < 4; k++) {
        ag.x = fmaf(e[k], Ag[k].x, ag.x);
        ag.y = fmaf(e[k], Ag[k].y, ag.y);
        ag.z = fmaf(e[k], Ag[k].z, ag.z);
        ag.w = fmaf(e[k], Ag[k].w, ag.w);
    }
    ag = xgrp_sum(ag);  // sum over all 16 rows; replicated across groups

    f4 comb;
    comb.x = fmaf(ag.x, inv, ie4.x);
    comb.y = fmaf(ag.y, inv, ie4.y);
    comb.z = fmaf(ag.z, inv, ie4.z);
    comb.w = fmaf(ag.w, inv, ie4.w);
    const float cc[4] = {comb.x, comb.y, comb.z, comb.w};

    // lite sums (read from LDS late; LDS latency is cheap to hide).
    f4 lu = {0.f, 0.f, 0.f, 0.f};
#pragma unroll
    for (int k = 0; k < 4; k++) {
        const f4 t = stage[wave][8 + k][lane];
        lu.x += t.x; lu.y += t.y; lu.z += t.z; lu.w += t.w;
    }
    lu = xgrp_sum(lu);
    f4 li = {0.f, 0.f, 0.f, 0.f};
#pragma unroll
    for (int k = 0; k < 4; k++) {
        const f4 t = stage[wave][12 + k][lane];
        li.x += t.x; li.y += t.y; li.z += t.z; li.w += t.w;
    }
    li = xgrp_sum(li);

    // 64x64 matvec: lane (g,s) accumulates d in [16g,16g+16) for out-chunk s.
    // comb replicated across groups; chunk 4g+(j>>2) lives in lane 20g+(j>>2).
    f4 acc = {0.f, 0.f, 0.f, 0.f};
#pragma unroll
    for (int j = 0; j < 16; j++) {
        const int d = 16 * g + j;
        const float cd = __shfl(cc[j & 3], 20 * g + (j >> 2), 64);
        const f4 w = W4[d * 16 + s];
        acc.x = fmaf(cd, w.x, acc.x);
        acc.y = fmaf(cd, w.y, acc.y);
        acc.z = fmaf(cd, w.z, acc.z);
        acc.w = fmaf(cd, w.w, acc.w);
    }
    acc = xgrp_sum(acc);
    const f4 bias = b4p[s];
    f4 item4;
    item4.x = tanhf(acc.x + bias.x);
    item4.y = tanhf(acc.y + bias.y);
    item4.z = tanhf(acc.z + bias.z);
    item4.w = tanhf(acc.w + bias.w);

    // final score: dot over 64 dims = in-group reduce over 16 chunks.
    f4 uf, itf;
    uf.x = 0.5f * fmaf(lu.x, 1.f / NNB, ue4.x);
    uf.y = 0.5f * fmaf(lu.y, 1.f / NNB, ue4.y);
    uf.z = 0.5f * fmaf(lu.z, 1.f / NNB, ue4.z);
    uf.w = 0.5f * fmaf(lu.w, 1.f / NNB, ue4.w);
    itf.x = 0.5f * fmaf(li.x, 1.f / NNB, item4.x);
    itf.y = 0.5f * fmaf(li.y, 1.f / NNB, item4.y);
    itf.z = 0.5f * fmaf(li.z, 1.f / NNB, item4.z);
    itf.w = 0.5f * fmaf(li.w, 1.f / NNB, item4.w);

    float p = dot4(uf, itf);
    p += __shfl_xor(p, 1, 64); p += __shfl_xor(p, 2, 64);
    p += __shfl_xor(p, 4, 64); p += __shfl_xor(p, 8, 64);

    if (lane == 0) out[b] = 1.0f / (1.0f + __expf(-p));
}

extern "C" void kernel_launch(void* const* d_in, const int* in_sizes, int n_in,
                              void* d_out, int out_size, void* d_ws, size_t ws_size,
                              hipStream_t stream)
{
    const int*   u             = (const int*)d_in[0];
    const int*   v             = (const int*)d_in[1];
    const int*   user_neighbor = (const int*)d_in[2];
    const int*   item_neighbor = (const int*)d_in[3];
    const int*   adj_ent       = (const int*)d_in[4];
    const int*   adj_rel       = (const int*)d_in[5];
    const float* usr_emb       = (const float*)d_in[6];
    const float* ent_emb       = (const float*)d_in[7];
    const float* rel_emb       = (const float*)d_in[8];
    const float* agg_W         = (const float*)d_in[9];
    const float* agg_b         = (const float*)d_in[10];
    float* out = (float*)d_out;

    constexpr int WPB = 2;  // 2 waves/block: 32 KB LDS -> 5 blocks/CU
    dim3 grid(BATCH / WPB), block(WPB * 64);
    klgcn_kernel<WPB><<<grid, block, 0, stream>>>(
        u, v, user_neighbor, item_neighbor, adj_ent, adj_rel,
        usr_emb, ent_emb, rel_emb, agg_W, agg_b, out);
}

// Round 9
// 156.331 us; speedup vs baseline: 1.0511x; 1.0511x over previous
//
#include <hip/hip_runtime.h>
#include <math.h>

#define DIM 64
#define NNB 16
#define BATCH 16384

// ext_vector float4: supports .xyzw and maps to a VGPR quad in "v" constraints.
typedef __attribute__((ext_vector_type(4))) float f4;

__device__ __forceinline__ float dot4(const f4 a, const f4 b) {
    return fmaf(a.x, b.x, fmaf(a.y, b.y, fmaf(a.z, b.z, a.w * b.w)));
}

// Sum across the 4 lane-groups (lanes differing in bits 4,5); chunk stays put.
__device__ __forceinline__ f4 xgrp_sum(f4 v) {
    v.x += __shfl_xor(v.x, 16, 64); v.y += __shfl_xor(v.y, 16, 64);
    v.z += __shfl_xor(v.z, 16, 64); v.w += __shfl_xor(v.w, 16, 64);
    v.x += __shfl_xor(v.x, 32, 64); v.y += __shfl_xor(v.y, 32, 64);
    v.z += __shfl_xor(v.z, 32, 64); v.w += __shfl_xor(v.w, 32, 64);
    return v;
}

template <int WPB>
__global__ __launch_bounds__(WPB * 64) void klgcn_kernel(
    const int* __restrict__ u, const int* __restrict__ v,
    const int* __restrict__ user_neighbor, const int* __restrict__ item_neighbor,
    const int* __restrict__ adj_ent, const int* __restrict__ adj_rel,
    const float* __restrict__ usr_emb, const float* __restrict__ ent_emb,
    const float* __restrict__ rel_emb, const float* __restrict__ agg_W,
    const float* __restrict__ agg_b, float* __restrict__ out)
{
    const int wave = threadIdx.x >> 6;
    const int lane = threadIdx.x & 63;
    const int g = lane >> 4;   // group 0..3: owns neighbor rows 4g..4g+3
    const int s = lane & 15;   // chunk 0..15: dims [4s, 4s+4)
    const int b = __builtin_amdgcn_readfirstlane(blockIdx.x * WPB + wave);

    const f4* __restrict__ usr4 = (const f4*)usr_emb;
    const f4* __restrict__ ent4 = (const f4*)ent_emb;
    const f4* __restrict__ rel4 = (const f4*)rel_emb;
    const f4* __restrict__ W4   = (const f4*)agg_W;
    const f4* __restrict__ b4p  = (const f4*)agg_b;
    const int4* __restrict__ it4 = (const int4*)item_neighbor;
    const int4* __restrict__ un4 = (const int4*)user_neighbor;
    const int4* __restrict__ ar4 = (const int4*)adj_rel;
    const int4* __restrict__ ae4 = (const int4*)adj_ent;

    const int ub = __builtin_amdgcn_readfirstlane(u[b]);
    const int vb = __builtin_amdgcn_readfirstlane(v[b]);

    // ---- Index loads (one int4 per table; lane-contiguous, no scratch).
    const int4 iar = ar4[vb * 4 + g];
    const int4 iae = ae4[vb * 4 + g];
    const int4 iit = it4[b * 4 + g];
    const int4 iun = un4[b * 4 + g];

    // ---- Direct rows (compiler-managed; any compiler waitcnt that undercounts
    // our hidden asm loads is strictly stricter than needed -> safe).
    const f4 ue4 = usr4[(size_t)ub * 16 + s];
    const f4 ie4 = ent4[(size_t)vb * 16 + s];

    // ---- Addresses for the 16 forced gathers (each instr = 4 rows = 1 KB/wave).
    const unsigned long long aRe0 = (unsigned long long)(rel4 + (size_t)iar.x * 16 + s);
    const unsigned long long aRe1 = (unsigned long long)(rel4 + (size_t)iar.y * 16 + s);
    const unsigned long long aRe2 = (unsigned long long)(rel4 + (size_t)iar.z * 16 + s);
    const unsigned long long aRe3 = (unsigned long long)(rel4 + (size_t)iar.w * 16 + s);
    const unsigned long long aAg0 = (unsigned long long)(ent4 + (size_t)iae.x * 16 + s);
    const unsigned long long aAg1 = (unsigned long long)(ent4 + (size_t)iae.y * 16 + s);
    const unsigned long long aAg2 = (unsigned long long)(ent4 + (size_t)iae.z * 16 + s);
    const unsigned long long aAg3 = (unsigned long long)(ent4 + (size_t)iae.w * 16 + s);
    const unsigned long long aLu0 = (unsigned long long)(usr4 + (size_t)iit.x * 16 + s);
    const unsigned long long aLu1 = (unsigned long long)(usr4 + (size_t)iit.y * 16 + s);
    const unsigned long long aLu2 = (unsigned long long)(usr4 + (size_t)iit.z * 16 + s);
    const unsigned long long aLu3 = (unsigned long long)(usr4 + (size_t)iit.w * 16 + s);
    const unsigned long long aLi0 = (unsigned long long)(ent4 + (size_t)iun.x * 16 + s);
    const unsigned long long aLi1 = (unsigned long long)(ent4 + (size_t)iun.y * 16 + s);
    const unsigned long long aLi2 = (unsigned long long)(ent4 + (size_t)iun.z * 16 + s);
    const unsigned long long aLi3 = (unsigned long long)(ent4 + (size_t)iun.w * 16 + s);

    f4 Re0, Re1, Re2, Re3, Ag0, Ag1, Ag2, Ag3;
    f4 Lu0, Lu1, Lu2, Lu3, Li0, Li1, Li2, Li3;

    // ---- Block A: 8 loads, opaque unit. "=&v" EARLY-CLOBBER: outputs must not
    // overlap the address pairs read by later instructions in this block.
    asm volatile(
        "global_load_dwordx4 %0, %8, off\n\t"
        "global_load_dwordx4 %1, %9, off\n\t"
        "global_load_dwordx4 %2, %10, off\n\t"
        "global_load_dwordx4 %3, %11, off\n\t"
        "global_load_dwordx4 %4, %12, off\n\t"
        "global_load_dwordx4 %5, %13, off\n\t"
        "global_load_dwordx4 %6, %14, off\n\t"
        "global_load_dwordx4 %7, %15, off"
        : "=&v"(Re0), "=&v"(Re1), "=&v"(Re2), "=&v"(Re3),
          "=&v"(Ag0), "=&v"(Ag1), "=&v"(Ag2), "=&v"(Ag3)
        : "v"(aRe0), "v"(aRe1), "v"(aRe2), "v"(aRe3),
          "v"(aAg0), "v"(aAg1), "v"(aAg2), "v"(aAg3));

    // ---- Block B: 8 loads (lite rows), same early-clobber discipline.
    asm volatile(
        "global_load_dwordx4 %0, %8, off\n\t"
        "global_load_dwordx4 %1, %9, off\n\t"
        "global_load_dwordx4 %2, %10, off\n\t"
        "global_load_dwordx4 %3, %11, off\n\t"
        "global_load_dwordx4 %4, %12, off\n\t"
        "global_load_dwordx4 %5, %13, off\n\t"
        "global_load_dwordx4 %6, %14, off\n\t"
        "global_load_dwordx4 %7, %15, off"
        : "=&v"(Lu0), "=&v"(Lu1), "=&v"(Lu2), "=&v"(Lu3),
          "=&v"(Li0), "=&v"(Li1), "=&v"(Li2), "=&v"(Li3)
        : "v"(aLu0), "v"(aLu1), "v"(aLu2), "v"(aLu3),
          "v"(aLi0), "v"(aLi1), "v"(aLi2), "v"(aLi3));

    // ---- Block C: vmcnt<=8 => the 8 Block-A loads (oldest) are complete.
    asm volatile("s_waitcnt vmcnt(8)"
                 : "+v"(Re0), "+v"(Re1), "+v"(Re2), "+v"(Re3),
                   "+v"(Ag0), "+v"(Ag1), "+v"(Ag2), "+v"(Ag3));

    const f4 Re[4] = {Re0, Re1, Re2, Re3};
    const f4 Ag[4] = {Ag0, Ag1, Ag2, Ag3};

    // ---- Attention scores: sc[k] = dot(ue, rel_row[4g+k]) (in-group reduce).
    float sc[4];
#pragma unroll
    for (int k = 0; k < 4; k++) {
        float p = dot4(ue4, Re[k]);
        p += __shfl_xor(p, 1, 64); p += __shfl_xor(p, 2, 64);
        p += __shfl_xor(p, 4, 64); p += __shfl_xor(p, 8, 64);
        sc[k] = p;
    }
    float m = fmaxf(fmaxf(sc[0], sc[1]), fmaxf(sc[2], sc[3]));
    m = fmaxf(m, __shfl_xor(m, 16, 64));
    m = fmaxf(m, __shfl_xor(m, 32, 64));
    float e[4];
    float ssum = 0.f;
#pragma unroll
    for (int k = 0; k < 4; k++) { e[k] = __expf(sc[k] - m); ssum += e[k]; }
    ssum += __shfl_xor(ssum, 16, 64);
    ssum += __shfl_xor(ssum, 32, 64);
    const float inv = 1.0f / ssum;

    // ---- neighbors_agg.
    f4 ag = {0.f, 0.f, 0.f, 0.f};
#pragma unroll
    for (int k = 0; k < 4; k++) {
        ag.x = fmaf(e[k], Ag[k].x, ag.x);
        ag.y = fmaf(e[k], Ag[k].y, ag.y);
        ag.z = fmaf(e[k], Ag[k].z, ag.z);
        ag.w = fmaf(e[k], Ag[k].w, ag.w);
    }
    ag = xgrp_sum(ag);

    f4 comb;
    comb.x = fmaf(ag.x, inv, ie4.x);
    comb.y = fmaf(ag.y, inv, ie4.y);
    comb.z = fmaf(ag.z, inv, ie4.z);
    comb.w = fmaf(ag.w, inv, ie4.w);
    const float cc[4] = {comb.x, comb.y, comb.z, comb.w};

    // ---- Block D: all loads complete; consume lite rows.
    asm volatile("s_waitcnt vmcnt(0)"
                 : "+v"(Lu0), "+v"(Lu1), "+v"(Lu2), "+v"(Lu3),
                   "+v"(Li0), "+v"(Li1), "+v"(Li2), "+v"(Li3));

    f4 lu;
    lu.x = Lu0.x + Lu1.x + Lu2.x + Lu3.x;
    lu.y = Lu0.y + Lu1.y + Lu2.y + Lu3.y;
    lu.z = Lu0.z + Lu1.z + Lu2.z + Lu3.z;
    lu.w = Lu0.w + Lu1.w + Lu2.w + Lu3.w;
    lu = xgrp_sum(lu);
    f4 li;
    li.x = Li0.x + Li1.x + Li2.x + Li3.x;
    li.y = Li0.y + Li1.y + Li2.y + Li3.y;
    li.z = Li0.z + Li1.z + Li2.z + Li3.z;
    li.w = Li0.w + Li1.w + Li2.w + Li3.w;
    li = xgrp_sum(li);

    // ---- 64x64 matvec: lane (g,s) accumulates d in [16g,16g+16) for out-chunk s.
    // comb replicated across groups; chunk 4g+(j>>2) lives in lane 20g+(j>>2).
    f4 acc = {0.f, 0.f, 0.f, 0.f};
#pragma unroll
    for (int j = 0; j < 16; j++) {
        const int d = 16 * g + j;
        const float cd = __shfl(cc[j & 3], 20 * g + (j >> 2), 64);
        const f4 w = W4[d * 16 + s];
        acc.x = fmaf(cd, w.x, acc.x);
        acc.y = fmaf(cd, w.y, acc.y);
        acc.z = fmaf(cd, w.z, acc.z);
        acc.w = fmaf(cd, w.w, acc.w);
    }
    acc = xgrp_sum(acc);
    const f4 bias = b4p[s];
    f4 item4;
    item4.x = tanhf(acc.x + bias.x);
    item4.y = tanhf(acc.y + bias.y);
    item4.z = tanhf(acc.z + bias.z);
    item4.w = tanhf(acc.w + bias.w);

    // ---- final score: dot over 64 dims = in-group reduce over 16 chunks.
    f4 uf, itf;
    uf.x = 0.5f * fmaf(lu.x, 1.f / NNB, ue4.x);
    uf.y = 0.5f * fmaf(lu.y, 1.f / NNB, ue4.y);
    uf.z = 0.5f * fmaf(lu.z, 1.f / NNB, ue4.z);
    uf.w = 0.5f * fmaf(lu.w, 1.f / NNB, ue4.w);
    itf.x = 0.5f * fmaf(li.x, 1.f / NNB, item4.x);
    itf.y = 0.5f * fmaf(li.y, 1.f / NNB, item4.y);
    itf.z = 0.5f * fmaf(li.z, 1.f / NNB, item4.z);
    itf.w = 0.5f * fmaf(li.w, 1.f / NNB, item4.w);

    float p = dot4(uf, itf);
    p += __shfl_xor(p, 1, 64); p += __shfl_xor(p, 2, 64);
    p += __shfl_xor(p, 4, 64); p += __shfl_xor(p, 8, 64);

    if (lane == 0) out[b] = 1.0f / (1.0f + __expf(-p));
}

extern "C" void kernel_launch(void* const* d_in, const int* in_sizes, int n_in,
                              void* d_out, int out_size, void* d_ws, size_t ws_size,
                              hipStream_t stream)
{
    const int*   u             = (const int*)d_in[0];
    const int*   v             = (const int*)d_in[1];
    const int*   user_neighbor = (const int*)d_in[2];
    const int*   item_neighbor = (const int*)d_in[3];
    const int*   adj_ent       = (const int*)d_in[4];
    const int*   adj_rel       = (const int*)d_in[5];
    const float* usr_emb       = (const float*)d_in[6];
    const float* ent_emb       = (const float*)d_in[7];
    const float* rel_emb       = (const float*)d_in[8];
    const float* agg_W         = (const float*)d_in[9];
    const float* agg_b         = (const float*)d_in[10];
    float* out = (float*)d_out;

    constexpr int WPB = 4;  // 4 waves/block, one batch element per wave, no LDS
    dim3 grid(BATCH / WPB), block(WPB * 64);
    klgcn_kernel<WPB><<<grid, block, 0, stream>>>(
        u, v, user_neighbor, item_neighbor, adj_ent, adj_rel,
        usr_emb, ent_emb, rel_emb, agg_W, agg_b, out);
}

// Round 10
// 154.987 us; speedup vs baseline: 1.0603x; 1.0087x over previous
//
#include <hip/hip_runtime.h>
#include <math.h>

#define DIM 64
#define NNB 16
#define BATCH 16384

typedef float4 f4;

__device__ __forceinline__ float dot4(const f4 a, const f4 b) {
    return fmaf(a.x, b.x, fmaf(a.y, b.y, fmaf(a.z, b.z, a.w * b.w)));
}

// Sum across the 4 lane-groups (lanes differing in bits 4,5); chunk stays put.
__device__ __forceinline__ f4 xgrp_sum(f4 v) {
    v.x += __shfl_xor(v.x, 16, 64); v.y += __shfl_xor(v.y, 16, 64);
    v.z += __shfl_xor(v.z, 16, 64); v.w += __shfl_xor(v.w, 16, 64);
    v.x += __shfl_xor(v.x, 32, 64); v.y += __shfl_xor(v.y, 32, 64);
    v.z += __shfl_xor(v.z, 32, 64); v.w += __shfl_xor(v.w, 32, 64);
    return v;
}

// Best-measured configuration (R4: 43.2 us, 2.4 TB/s HBM, FETCH ~= compulsory).
// Evidence across R2/R4/R6/R7/R9: random 256B-row gathers cap at ~2.3-2.5 TB/s
// HBM-visible regardless of occupancy (18-62%) or outstanding/wave (2-16 KB);
// bytes are ~1.3x the coverage floor. This kernel sits ~3% off that roofline.
template <int WPB>
__global__ __launch_bounds__(WPB * 64, 4) void klgcn_kernel(
    const int* __restrict__ u, const int* __restrict__ v,
    const int* __restrict__ user_neighbor, const int* __restrict__ item_neighbor,
    const int* __restrict__ adj_ent, const int* __restrict__ adj_rel,
    const float* __restrict__ usr_emb, const float* __restrict__ ent_emb,
    const float* __restrict__ rel_emb, const float* __restrict__ agg_W,
    const float* __restrict__ agg_b, float* __restrict__ out)
{
    const int wave = threadIdx.x >> 6;
    const int lane = threadIdx.x & 63;
    const int g = lane >> 4;   // group 0..3: owns neighbor rows 4g..4g+3
    const int s = lane & 15;   // chunk 0..15: dims [4s, 4s+4)
    const int b = __builtin_amdgcn_readfirstlane(blockIdx.x * WPB + wave);

    const f4* __restrict__ usr4 = (const f4*)usr_emb;
    const f4* __restrict__ ent4 = (const f4*)ent_emb;
    const f4* __restrict__ rel4 = (const f4*)rel_emb;
    const f4* __restrict__ W4   = (const f4*)agg_W;
    const f4* __restrict__ b4p  = (const f4*)agg_b;
    const int4* __restrict__ it4 = (const int4*)item_neighbor;
    const int4* __restrict__ un4 = (const int4*)user_neighbor;
    const int4* __restrict__ ar4 = (const int4*)adj_rel;
    const int4* __restrict__ ae4 = (const int4*)adj_ent;

    const int ub = __builtin_amdgcn_readfirstlane(u[b]);
    const int vb = __builtin_amdgcn_readfirstlane(v[b]);

    // ---- Per-lane contiguous index loads: one int4 per table (no scratch).
    const int4 iit = it4[b * 4 + g];          // item_neighbor rows 4g..4g+3
    const int4 iun = un4[b * 4 + g];          // user_neighbor rows 4g..4g+3
    const int4 iar = ar4[vb * 4 + g];         // adj_rel rows 4g..4g+3
    const int4 iae = ae4[vb * 4 + g];         // adj_ent rows 4g..4g+3

    // ---- Direct rows.
    const f4 ue4 = usr4[(long)ub * 16 + s];
    const f4 ie4 = ent4[(long)vb * 16 + s];

    // ---- Row gathers: each instruction fetches 4 distinct rows (1 KB/wave).
    f4 Re[4], Ag[4], Lu[4], Li[4];
    Re[0] = rel4[iar.x * 16 + s];
    Re[1] = rel4[iar.y * 16 + s];
    Re[2] = rel4[iar.z * 16 + s];
    Re[3] = rel4[iar.w * 16 + s];
    Ag[0] = ent4[(long)iae.x * 16 + s];
    Ag[1] = ent4[(long)iae.y * 16 + s];
    Ag[2] = ent4[(long)iae.z * 16 + s];
    Ag[3] = ent4[(long)iae.w * 16 + s];
    Lu[0] = usr4[(long)iit.x * 16 + s];
    Lu[1] = usr4[(long)iit.y * 16 + s];
    Lu[2] = usr4[(long)iit.z * 16 + s];
    Lu[3] = usr4[(long)iit.w * 16 + s];
    Li[0] = ent4[(long)iun.x * 16 + s];
    Li[1] = ent4[(long)iun.y * 16 + s];
    Li[2] = ent4[(long)iun.z * 16 + s];
    Li[3] = ent4[(long)iun.w * 16 + s];

    // ---- Attention scores: sc[k] = dot(ue, rel_row[4g+k]) (in-group reduce).
    float sc[4];
#pragma unroll
    for (int k = 0; k < 4; k++) {
        float p = dot4(ue4, Re[k]);
        p += __shfl_xor(p, 1, 64); p += __shfl_xor(p, 2, 64);
        p += __shfl_xor(p, 4, 64); p += __shfl_xor(p, 8, 64);
        sc[k] = p;  // identical across the 16 lanes of group g
    }
    float m = fmaxf(fmaxf(sc[0], sc[1]), fmaxf(sc[2], sc[3]));
    m = fmaxf(m, __shfl_xor(m, 16, 64));
    m = fmaxf(m, __shfl_xor(m, 32, 64));
    float e[4];
    float ssum = 0.f;
#pragma unroll
    for (int k = 0; k < 4; k++) { e[k] = __expf(sc[k] - m); ssum += e[k]; }
    ssum += __shfl_xor(ssum, 16, 64);
    ssum += __shfl_xor(ssum, 32, 64);
    const float inv = 1.0f / ssum;

    // ---- neighbors_agg: this lane holds the attn weights for its own rows.
    f4 ag = {0.f, 0.f, 0.f, 0.f};
#pragma unroll
    for (int k = 0; k < 4; k++) {
        ag.x = fmaf(e[k], Ag[k].x, ag.x);
        ag.y = fmaf(e[k], Ag[k].y, ag.y);
        ag.z = fmaf(e[k], Ag[k].z, ag.z);
        ag.w = fmaf(e[k], Ag[k].w, ag.w);
    }
    ag = xgrp_sum(ag);  // sum over all 16 rows; replicated across groups

    f4 comb;
    comb.x = fmaf(ag.x, inv, ie4.x);
    comb.y = fmaf(ag.y, inv, ie4.y);
    comb.z = fmaf(ag.z, inv, ie4.z);
    comb.w = fmaf(ag.w, inv, ie4.w);
    const float cc[4] = {comb.x, comb.y, comb.z, comb.w};

    // ---- lite sums.
    f4 lu;
    lu.x = Lu[0].x + Lu[1].x + Lu[2].x + Lu[3].x;
    lu.y = Lu[0].y + Lu[1].y + Lu[2].y + Lu[3].y;
    lu.z = Lu[0].z + Lu[1].z + Lu[2].z + Lu[3].z;
    lu.w = Lu[0].w + Lu[1].w + Lu[2].w + Lu[3].w;
    lu = xgrp_sum(lu);
    f4 li;
    li.x = Li[0].x + Li[1].x + Li[2].x + Li[3].x;
    li.y = Li[0].y + Li[1].y + Li[2].y + Li[3].y;
    li.z = Li[0].z + Li[1].z + Li[2].z + Li[3].z;
    li.w = Li[0].w + Li[1].w + Li[2].w + Li[3].w;
    li = xgrp_sum(li);

    // ---- 64x64 matvec: lane (g,s) accumulates d in [16g,16g+16) for out-chunk s.
    // comb replicated across groups; chunk 4g+(j>>2) lives in lane 20g+(j>>2).
    f4 acc = {0.f, 0.f, 0.f, 0.f};
#pragma unroll
    for (int j = 0; j < 16; j++) {
        const int d = 16 * g + j;
        const float cd = __shfl(cc[j & 3], 20 * g + (j >> 2), 64);
        const f4 w = W4[d * 16 + s];
        acc.x = fmaf(cd, w.x, acc.x);
        acc.y = fmaf(cd, w.y, acc.y);
        acc.z = fmaf(cd, w.z, acc.z);
        acc.w = fmaf(cd, w.w, acc.w);
    }
    acc = xgrp_sum(acc);
    const f4 bias = b4p[s];
    f4 item4;
    item4.x = tanhf(acc.x + bias.x);
    item4.y = tanhf(acc.y + bias.y);
    item4.z = tanhf(acc.z + bias.z);
    item4.w = tanhf(acc.w + bias.w);

    // ---- final score: dot over 64 dims = in-group reduce over 16 chunks.
    f4 uf, itf;
    uf.x = 0.5f * fmaf(lu.x, 1.f / NNB, ue4.x);
    uf.y = 0.5f * fmaf(lu.y, 1.f / NNB, ue4.y);
    uf.z = 0.5f * fmaf(lu.z, 1.f / NNB, ue4.z);
    uf.w = 0.5f * fmaf(lu.w, 1.f / NNB, ue4.w);
    itf.x = 0.5f * fmaf(li.x, 1.f / NNB, item4.x);
    itf.y = 0.5f * fmaf(li.y, 1.f / NNB, item4.y);
    itf.z = 0.5f * fmaf(li.z, 1.f / NNB, item4.z);
    itf.w = 0.5f * fmaf(li.w, 1.f / NNB, item4.w);

    float p = dot4(uf, itf);
    p += __shfl_xor(p, 1, 64); p += __shfl_xor(p, 2, 64);
    p += __shfl_xor(p, 4, 64); p += __shfl_xor(p, 8, 64);

    if (lane == 0) out[b] = 1.0f / (1.0f + __expf(-p));
}

extern "C" void kernel_launch(void* const* d_in, const int* in_sizes, int n_in,
                              void* d_out, int out_size, void* d_ws, size_t ws_size,
                              hipStream_t stream)
{
    const int*   u             = (const int*)d_in[0];
    const int*   v             = (const int*)d_in[1];
    const int*   user_neighbor = (const int*)d_in[2];
    const int*   item_neighbor = (const int*)d_in[3];
    const int*   adj_ent       = (const int*)d_in[4];
    const int*   adj_rel       = (const int*)d_in[5];
    const float* usr_emb       = (const float*)d_in[6];
    const float* ent_emb       = (const float*)d_in[7];
    const float* rel_emb       = (const float*)d_in[8];
    const float* agg_W         = (const float*)d_in[9];
    const float* agg_b         = (const float*)d_in[10];
    float* out = (float*)d_out;

    constexpr int WPB = 4;  // 4 waves/block, one batch element per wave
    dim3 grid(BATCH / WPB), block(WPB * 64);
    klgcn_kernel<WPB><<<grid, block, 0, stream>>>(
        u, v, user_neighbor, item_neighbor, adj_ent, adj_rel,
        usr_emb, ent_emb, rel_emb, agg_W, agg_b, out);
}